// Round 1
// baseline (143.833 us; speedup 1.0000x reference)
//
#include <hip/hip_runtime.h>

typedef float f32x4 __attribute__((ext_vector_type(4)));
typedef short s16x8 __attribute__((ext_vector_type(8)));
typedef unsigned short u16x4 __attribute__((ext_vector_type(4)));

#define NB 8
#define NN 2048
#define FIN 512
#define FOUT 256

__device__ __forceinline__ unsigned short f2bf(float f) {
  unsigned u = __builtin_bit_cast(unsigned, f);
  u += 0x7fffu + ((u >> 16) & 1u);
  return (unsigned short)(u >> 16);
}

// ---------------- kernel 1: v1 = W @ (ht @ a1), v2 = W @ (ht @ a2) ----------------
__global__ void prep_vecs_k(const float* __restrict__ W, const float* __restrict__ HT,
                            const float* __restrict__ A, float* __restrict__ v1,
                            float* __restrict__ v2) {
  __shared__ float w1[256], w2[256];
  int t = threadIdx.x;  // 256 threads
  float s1 = 0.f, s2 = 0.f;
  for (int k = 0; k < 64; k++) {
    float h = HT[t * 64 + k];
    s1 += h * A[k];
    s2 += h * A[64 + k];
  }
  w1[t] = s1;
  w2[t] = s2;
  __syncthreads();
  for (int c = t; c < FIN; c += 256) {
    float a1 = 0.f, a2 = 0.f;
    for (int f = 0; f < FOUT; f++) {
      float w = W[c * FOUT + f];
      a1 += w * w1[f];
      a2 += w * w2[f];
    }
    v1[c] = a1;
    v2[c] = a2;
  }
}

// ---------------- kernel 2: wT[f][c] = bf16(W[c][f]) ----------------
__global__ void prep_wT_k(const float* __restrict__ W, unsigned short* __restrict__ wT) {
  int id = blockIdx.x * 256 + threadIdx.x;  // 131072 total
  int f = id >> 9, c = id & 511;
  wT[id] = f2bf(W[c * FOUT + f]);
}

// ---------------- kernel 3: f1[row] = X[row]·v1, f2[row] = X[row]·v2 ----------------
__global__ void f12_k(const float* __restrict__ inp, const float* __restrict__ v1,
                      const float* __restrict__ v2, float* __restrict__ f1,
                      float* __restrict__ f2) {
  int row = blockIdx.x * 4 + (threadIdx.x >> 6);
  int lane = threadIdx.x & 63;
  const float* rp = inp + (size_t)row * FIN + lane * 8;
  float4 x0 = *(const float4*)rp;
  float4 x1 = *(const float4*)(rp + 4);
  float4 a0 = *(const float4*)(v1 + lane * 8);
  float4 a1 = *(const float4*)(v1 + lane * 8 + 4);
  float4 b0 = *(const float4*)(v2 + lane * 8);
  float4 b1 = *(const float4*)(v2 + lane * 8 + 4);
  float s1 = x0.x * a0.x + x0.y * a0.y + x0.z * a0.z + x0.w * a0.w +
             x1.x * a1.x + x1.y * a1.y + x1.z * a1.z + x1.w * a1.w;
  float s2 = x0.x * b0.x + x0.y * b0.y + x0.z * b0.z + x0.w * b0.w +
             x1.x * b1.x + x1.y * b1.y + x1.z * b1.z + x1.w * b1.w;
  for (int o = 32; o > 0; o >>= 1) {
    s1 += __shfl_xor(s1, o);
    s2 += __shfl_xor(s2, o);
  }
  if (lane == 0) {
    f1[row] = s1;
    f2[row] = s2;
  }
}

// ---------------- kernel 4: hT[b][f][j] = (X @ W)^T in bf16 via MFMA ----------------
// D = A·B with A = wT (M=f, K=c), B = X^T (K=c, N=j rows of input).
__global__ __launch_bounds__(512) void gemm1_k(const float* __restrict__ inp,
                                               const unsigned short* __restrict__ wT,
                                               unsigned short* __restrict__ hT) {
  int tid = threadIdx.x;
  int w = tid >> 6, l = tid & 63, lr = l & 15, lg = l >> 4;
  int jtile = blockIdx.x * 64;  // global row base (0..16384)
  f32x4 acc[2][4] = {};
  for (int c0 = 0; c0 < FIN; c0 += 32) {
    s16x8 af[2];
#pragma unroll
    for (int mf = 0; mf < 2; mf++) {
      int f = w * 32 + mf * 16 + lr;
      af[mf] = *(const s16x8*)(wT + (size_t)f * FIN + c0 + lg * 8);
    }
    s16x8 bfv[4];
#pragma unroll
    for (int nf = 0; nf < 4; nf++) {
      int jg = jtile + nf * 16 + lr;
      const float* p = inp + (size_t)jg * FIN + c0 + lg * 8;
      float4 x0 = *(const float4*)p;
      float4 x1 = *(const float4*)(p + 4);
      s16x8 t;
      t[0] = (short)f2bf(x0.x); t[1] = (short)f2bf(x0.y);
      t[2] = (short)f2bf(x0.z); t[3] = (short)f2bf(x0.w);
      t[4] = (short)f2bf(x1.x); t[5] = (short)f2bf(x1.y);
      t[6] = (short)f2bf(x1.z); t[7] = (short)f2bf(x1.w);
      bfv[nf] = t;
    }
#pragma unroll
    for (int mf = 0; mf < 2; mf++)
#pragma unroll
      for (int nf = 0; nf < 4; nf++)
        acc[mf][nf] =
            __builtin_amdgcn_mfma_f32_16x16x32_bf16(af[mf], bfv[nf], acc[mf][nf], 0, 0, 0);
  }
  int bb = jtile >> 11, jl = jtile & 2047;
#pragma unroll
  for (int mf = 0; mf < 2; mf++)
#pragma unroll
    for (int nf = 0; nf < 4; nf++)
#pragma unroll
      for (int r = 0; r < 4; r++) {
        int f = w * 32 + mf * 16 + lg * 4 + r;
        int j = jl + nf * 16 + lr;
        hT[((size_t)bb * FOUT + f) * (size_t)NN + j] = f2bf(acc[mf][nf][r]);
      }
}

// ---------------- kernel 5: fused masked-softmax + PV + ELU ----------------
// Per block: batch b, 64 i-rows. Loop j in steps of 32:
//   phase A: p~[i][j] = adj ? exp(lrelu(f1[i]+f2[j])) : 0  -> swizzled LDS bf16 tile
//   phase B: acc += p~ (A-frag from LDS) x hT (B-frag from global, L2-hot)
// Epilogue: out = elu(acc / l_i)
__global__ __launch_bounds__(512) void pv_k(const int* __restrict__ adj,
                                            const unsigned short* __restrict__ hT,
                                            const float* __restrict__ f1,
                                            const float* __restrict__ f2,
                                            float* __restrict__ out) {
  __shared__ float f2s[NN];
  __shared__ float f1s[64];
  __shared__ float lsum[64];
  __shared__ unsigned short ptile[64 * 32];

  int tid = threadIdx.x;
  int b = blockIdx.x >> 5;
  int itile = (blockIdx.x & 31) * 64;

  for (int k = tid; k < NN; k += 512) f2s[k] = f2[b * NN + k];
  if (tid < 64) f1s[tid] = f1[b * NN + itile + tid];
  __syncthreads();

  int w = tid >> 6, l = tid & 63, lr = l & 15, lg = l >> 4;
  int wm = w >> 2, wn = w & 3;  // 2 (M) x 4 (N) wave grid
  int iloc = tid >> 3, s8 = tid & 7;

  const int* adjrow = adj + ((size_t)(b * NN + itile + iloc)) * NN + s8 * 4;
  const unsigned short* hTb = hT + (size_t)b * FOUT * NN;
  float fi = f1s[iloc];
  float ls = 0.f;
  f32x4 acc[2][4] = {};

  char* pbase = (char*)ptile;
  // write: 8B slot s8 of row iloc, 16B-chunk XOR-swizzled by (iloc&3)
  int wr_off = iloc * 64 + ((((s8 >> 1) ^ (iloc & 3)) << 4) | ((s8 & 1) << 3));

  int4 adv = *(const int4*)adjrow;
  for (int jb = 0; jb < NN; jb += 32) {
    // ---- phase A: compute 4 p-values, pack bf16, store to LDS ----
    float4 fv = *(const float4*)&f2s[jb + s8 * 4];
    u16x4 pb;
    {
      float e0 = fi + fv.x, e1 = fi + fv.y, e2 = fi + fv.z, e3 = fi + fv.w;
      e0 = fmaxf(e0, 0.2f * e0);
      e1 = fmaxf(e1, 0.2f * e1);
      e2 = fmaxf(e2, 0.2f * e2);
      e3 = fmaxf(e3, 0.2f * e3);
      float p0 = (adv.x > 0) ? __expf(e0) : 0.f;
      float p1 = (adv.y > 0) ? __expf(e1) : 0.f;
      float p2 = (adv.z > 0) ? __expf(e2) : 0.f;
      float p3 = (adv.w > 0) ? __expf(e3) : 0.f;
      ls += p0 + p1 + p2 + p3;
      pb[0] = f2bf(p0); pb[1] = f2bf(p1); pb[2] = f2bf(p2); pb[3] = f2bf(p3);
    }
    *(u16x4*)(pbase + wr_off) = pb;

    // prefetch next adj row chunk (hides HBM latency under phase B)
    if (jb + 32 < NN) adv = *(const int4*)(adjrow + jb + 32);

    // prefetch B fragments (independent of LDS tile)
    s16x8 bfr[4];
#pragma unroll
    for (int nf = 0; nf < 4; nf++) {
      int f = wn * 64 + nf * 16 + lr;
      bfr[nf] = *(const s16x8*)(hTb + (size_t)f * NN + jb + lg * 8);
    }

    __syncthreads();  // p-tile visible

    // ---- phase B: A-frags from LDS, 8 MFMA ----
    s16x8 afr[2];
#pragma unroll
    for (int mf = 0; mf < 2; mf++) {
      int i = wm * 32 + mf * 16 + lr;
      afr[mf] = *(s16x8*)(pbase + i * 64 + ((lg ^ (i & 3)) << 4));
    }
#pragma unroll
    for (int mf = 0; mf < 2; mf++)
#pragma unroll
      for (int nf = 0; nf < 4; nf++)
        acc[mf][nf] =
            __builtin_amdgcn_mfma_f32_16x16x32_bf16(afr[mf], bfr[nf], acc[mf][nf], 0, 0, 0);

    __syncthreads();  // reads done before next overwrite
  }

  // ---- denominator reduce: 8 threads (consecutive lanes) per row ----
  ls += __shfl_xor(ls, 1);
  ls += __shfl_xor(ls, 2);
  ls += __shfl_xor(ls, 4);
  if (s8 == 0) lsum[iloc] = ls;
  __syncthreads();

  // ---- epilogue: divide, ELU, store f32 ----
#pragma unroll
  for (int mf = 0; mf < 2; mf++)
#pragma unroll
    for (int nf = 0; nf < 4; nf++)
#pragma unroll
      for (int r = 0; r < 4; r++) {
        int i = wm * 32 + mf * 16 + lg * 4 + r;
        int fcol = wn * 64 + nf * 16 + lr;
        float v = acc[mf][nf][r] / lsum[i];
        v = (v > 0.f) ? v : expm1f(v);
        out[((size_t)(b * NN + itile + i)) * FOUT + fcol] = v;
      }
}

extern "C" void kernel_launch(void* const* d_in, const int* in_sizes, int n_in,
                              void* d_out, int out_size, void* d_ws, size_t ws_size,
                              hipStream_t stream) {
  const float* inp = (const float*)d_in[0];   // [8][2048][512] f32
  const int* adj   = (const int*)d_in[1];     // [8][2048][2048] i32
  const float* W   = (const float*)d_in[2];   // [512][256] f32
  const float* HT  = (const float*)d_in[3];   // [256][64] f32
  const float* A   = (const float*)d_in[4];   // [128][1] f32
  float* out = (float*)d_out;                 // [8][2048][256] f32

  char* ws = (char*)d_ws;
  float* v1 = (float*)ws;                            // 512 f32
  float* v2 = v1 + 512;                              // 512 f32
  float* f1 = (float*)(ws + 4096);                   // 16384 f32
  float* f2 = (float*)(ws + 69632);                  // 16384 f32
  unsigned short* wT = (unsigned short*)(ws + 135168);   // 256x512 bf16
  unsigned short* hT = (unsigned short*)(ws + 397312);   // 8x256x2048 bf16

  hipLaunchKernelGGL(prep_vecs_k, dim3(1), dim3(256), 0, stream, W, HT, A, v1, v2);
  hipLaunchKernelGGL(prep_wT_k, dim3(512), dim3(256), 0, stream, W, wT);
  hipLaunchKernelGGL(f12_k, dim3(4096), dim3(256), 0, stream, inp, v1, v2, f1, f2);
  hipLaunchKernelGGL(gemm1_k, dim3(256), dim3(512), 0, stream, inp, wT, hT);
  hipLaunchKernelGGL(pv_k, dim3(256), dim3(512), 0, stream, adj, hT, f1, f2, out);
}